// Round 5
// baseline (498.562 us; speedup 1.0000x reference)
//
#include <hip/hip_runtime.h>
#include <hip/hip_bf16.h>
#include <stdint.h>

#define D 128
#define H 8
#define DK 16

#define SCAN_BLK 256
#define SCAN_ITEMS 8
#define SCAN_TILE (SCAN_BLK * SCAN_ITEMS)

typedef __attribute__((ext_vector_type(8))) short bf16x8;
typedef __attribute__((ext_vector_type(4))) float f32x4;

// ---------- bf16 helpers ----------
__device__ __forceinline__ unsigned short f2bf(float f) {
    unsigned int u = __float_as_uint(f);
    u = u + 0x7fffu + ((u >> 16) & 1u);      // round-to-nearest-even
    return (unsigned short)(u >> 16);
}
__device__ __forceinline__ float bfl(unsigned int u) { return __uint_as_float(u << 16); }
__device__ __forceinline__ float bfh(unsigned int u) { return __uint_as_float(u & 0xffff0000u); }
__device__ __forceinline__ unsigned int pack2(unsigned short a, unsigned short b) {
    return (unsigned int)a | ((unsigned int)b << 16);
}
__device__ __forceinline__ void unpack8(uint4 u, float* o) {
    o[0]=bfl(u.x); o[1]=bfh(u.x); o[2]=bfl(u.y); o[3]=bfh(u.y);
    o[4]=bfl(u.z); o[5]=bfh(u.z); o[6]=bfl(u.w); o[7]=bfh(u.w);
}

// ---------- combined prep: W^T transposes + relation folds + cnt zeroing ----------
// blocks [0,64): plain transpose of 4 mats (16 tiles each)
// blocks [64,112): fold 6 variants x 8 heads
// blocks [112,...): zero cnt[S]
struct WTIn  { const float* w[4]; };
struct WTOut { unsigned short* wt[4]; };
struct FoldArgs {
    const float* W[6]; const float* R[6]; const float* b[6];
    unsigned short* WT[6]; float* bf[6]; int mode[6];
};

__global__ __launch_bounds__(256) void prep_kernel(WTIn in, WTOut out, FoldArgs a,
                                                   int* __restrict__ cnt, int S) {
    __shared__ float tile[32][33];
    __shared__ float Wl[128 * 17];
    __shared__ float Rl[256];
    int bid = blockIdx.x;
    int tid = threadIdx.x;
    if (bid < 64) {
        int mat = bid >> 4;
        int t = bid & 15;
        int k0 = (t >> 2) * 32, c0 = (t & 3) * 32;
        const float* W = in.w[mat];
        unsigned short* WT = out.wt[mat];
        int lr = tid >> 5, lc = tid & 31;
        #pragma unroll
        for (int p = 0; p < 4; ++p)
            tile[p * 8 + lr][lc] = W[(size_t)(k0 + p * 8 + lr) * D + c0 + lc];
        __syncthreads();
        #pragma unroll
        for (int p = 0; p < 4; ++p)
            WT[(size_t)(c0 + p * 8 + lr) * D + k0 + lc] = f2bf(tile[lc][p * 8 + lr]);
    } else if (bid < 112) {
        int v = (bid - 64) >> 3, h = (bid - 64) & 7;
        const float* W = a.W[v];
        #pragma unroll
        for (int p = 0; p < 8; ++p) {
            int idx = p * 256 + tid;
            int c = idx >> 4, i = idx & 15;
            Wl[c * 17 + i] = W[(size_t)c * D + h * 16 + i];
        }
        Rl[tid] = a.R[v][h * 256 + tid];
        __syncthreads();
        int mode = a.mode[v];
        int c = tid & 127, jb = (tid >> 7) * 8;
        #pragma unroll
        for (int jj = 0; jj < 8; ++jj) {
            int j = jb + jj;
            float s = 0.f;
            #pragma unroll
            for (int i = 0; i < 16; ++i)
                s = fmaf(Wl[c * 17 + i], mode ? Rl[i * 16 + j] : Rl[j * 16 + i], s);
            a.WT[v][(size_t)(h * 16 + j) * D + c] = f2bf(s);
        }
        if (tid < 16) {
            const float* b = a.b[v];
            float s = 0.f;
            #pragma unroll
            for (int i = 0; i < 16; ++i)
                s = fmaf(b[h * 16 + i], mode ? Rl[i * 16 + tid] : Rl[tid * 16 + i], s);
            a.bf[v][h * 16 + tid] = s;
        }
    } else {
        int base = (bid - 112) * 1024 + tid * 4;
        if (base + 4 <= S) {
            *(int4*)&cnt[base] = make_int4(0, 0, 0, 0);
        } else {
            for (int i = base; i < S; ++i) cnt[i] = 0;
        }
    }
}

// ---------- MFMA multi-output projection ----------
// mode: 0 = plain [row*128+col]; 1 = kv slot0; 2 = kv slot1
// kv layout: [row][head][2][16] ushorts -> row stride 256
__device__ __forceinline__ size_t out_addr(int mode, int row, int col) {
    if (mode == 0) return (size_t)row * 128 + col;
    return (size_t)row * 256 + (col >> 4) * 32 + (mode - 1) * 16 + (col & 15);
}

#define ASTRIDE 136
template<int NMAT> struct ProjArgs {
    const unsigned short* wt[NMAT];
    const float* bias[NMAT];
    unsigned short* out[NMAT];
    unsigned short* out2[NMAT];
    int mode[NMAT];
    int mode2[NMAT];
};

template<int NMAT>
__global__ __launch_bounds__(256, 2) void proj_all_kernel(
    const float* __restrict__ X, ProjArgs<NMAT> a, int N)
{
    __shared__ unsigned short As[64 * ASTRIDE];
    const int tid = threadIdx.x;
    const int w = tid >> 6;
    const int l = tid & 63;
    const int row0 = blockIdx.x * 64;

    #pragma unroll
    for (int p = 0; p < 8; ++p) {
        int f = p * 256 + tid;
        int r = f >> 5;
        int c4 = f & 31;
        int row = row0 + r; if (row >= N) row = N - 1;
        float4 xv = *(const float4*)&X[(size_t)row * D + c4 * 4];
        unsigned int lo = pack2(f2bf(xv.x), f2bf(xv.y));
        unsigned int hi = pack2(f2bf(xv.z), f2bf(xv.w));
        *(uint2*)&As[r * ASTRIDE + c4 * 4] = make_uint2(lo, hi);
    }
    __syncthreads();

    const int lrow = l & 15;
    const int lk8 = (l >> 4) * 8;

    #pragma unroll
    for (int m = 0; m < NMAT; ++m) {
        const unsigned short* WT = a.wt[m];
        bf16x8 bfrag[2][4];
        #pragma unroll
        for (int cf = 0; cf < 2; ++cf)
            #pragma unroll
            for (int kc = 0; kc < 4; ++kc)
                bfrag[cf][kc] = *(const bf16x8*)&WT[(size_t)(w * 32 + cf * 16 + lrow) * D + kc * 32 + lk8];

        f32x4 acc[4][2];
        #pragma unroll
        for (int rf = 0; rf < 4; ++rf) {
            acc[rf][0] = (f32x4){0.f, 0.f, 0.f, 0.f};
            acc[rf][1] = (f32x4){0.f, 0.f, 0.f, 0.f};
        }
        #pragma unroll
        for (int rf = 0; rf < 4; ++rf) {
            bf16x8 afrag[4];
            #pragma unroll
            for (int kc = 0; kc < 4; ++kc)
                afrag[kc] = *(const bf16x8*)&As[(rf * 16 + lrow) * ASTRIDE + kc * 32 + lk8];
            #pragma unroll
            for (int kc = 0; kc < 4; ++kc) {
                acc[rf][0] = __builtin_amdgcn_mfma_f32_16x16x32_bf16(afrag[kc], bfrag[0][kc], acc[rf][0], 0, 0, 0);
                acc[rf][1] = __builtin_amdgcn_mfma_f32_16x16x32_bf16(afrag[kc], bfrag[1][kc], acc[rf][1], 0, 0, 0);
            }
        }
        float bias0 = a.bias[m][w * 32 + lrow];
        float bias1 = a.bias[m][w * 32 + 16 + lrow];
        unsigned short* O = a.out[m];
        unsigned short* O2 = a.out2[m];
        int md = a.mode[m], md2 = a.mode2[m];
        #pragma unroll
        for (int rf = 0; rf < 4; ++rf) {
            #pragma unroll
            for (int r = 0; r < 4; ++r) {
                int row = row0 + rf * 16 + (l >> 4) * 4 + r;
                if (row < N) {
                    int c0 = w * 32 + lrow;
                    unsigned short v0 = f2bf(acc[rf][0][r] + bias0);
                    unsigned short v1 = f2bf(acc[rf][1][r] + bias1);
                    O[out_addr(md, row, c0)] = v0;
                    O[out_addr(md, row, c0 + 16)] = v1;
                    if (O2) {
                        O2[out_addr(md2, row, c0)] = v0;
                        O2[out_addr(md2, row, c0 + 16)] = v1;
                    }
                }
            }
        }
    }
}

// ---------- MFMA out-GEMM: O = (relu-comb(T) @ Wa + b)*alpha + X*(1-alpha), fp32 out ----------
template<int NSRC>
__global__ __launch_bounds__(256) void out_gemm_mfma_kernel(
    const unsigned short* __restrict__ T1, const unsigned short* __restrict__ T2,
    const unsigned short* __restrict__ WT, const float* __restrict__ b,
    const float* __restrict__ skip, const float* __restrict__ X,
    float* __restrict__ O, int N)
{
    __shared__ unsigned short As[64 * ASTRIDE];
    const int tid = threadIdx.x;
    const int w = tid >> 6;
    const int l = tid & 63;
    const int row0 = blockIdx.x * 64;

    #pragma unroll
    for (int p = 0; p < 4; ++p) {
        int idx = p * 256 + tid;
        int r = idx >> 4;
        int c8 = idx & 15;
        int row = row0 + r; if (row >= N) row = N - 1;
        uint4 tv = *(const uint4*)&T1[(size_t)row * D + c8 * 8];
        float v[8]; unpack8(tv, v);
        #pragma unroll
        for (int i = 0; i < 8; ++i) v[i] = fmaxf(v[i], 0.f);
        if (NSRC == 2) {
            uint4 uv = *(const uint4*)&T2[(size_t)row * D + c8 * 8];
            float u[8]; unpack8(uv, u);
            #pragma unroll
            for (int i = 0; i < 8; ++i) v[i] = 0.5f * (v[i] + fmaxf(u[i], 0.f));
        }
        uint4 pk;
        pk.x = pack2(f2bf(v[0]), f2bf(v[1]));
        pk.y = pack2(f2bf(v[2]), f2bf(v[3]));
        pk.z = pack2(f2bf(v[4]), f2bf(v[5]));
        pk.w = pack2(f2bf(v[6]), f2bf(v[7]));
        *(uint4*)&As[r * ASTRIDE + c8 * 8] = pk;
    }
    __syncthreads();

    const int lrow = l & 15;
    const int lk8 = (l >> 4) * 8;

    bf16x8 bfrag[2][4];
    #pragma unroll
    for (int cf = 0; cf < 2; ++cf)
        #pragma unroll
        for (int kc = 0; kc < 4; ++kc)
            bfrag[cf][kc] = *(const bf16x8*)&WT[(size_t)(w * 32 + cf * 16 + lrow) * D + kc * 32 + lk8];

    f32x4 acc[4][2];
    #pragma unroll
    for (int rf = 0; rf < 4; ++rf) {
        acc[rf][0] = (f32x4){0.f, 0.f, 0.f, 0.f};
        acc[rf][1] = (f32x4){0.f, 0.f, 0.f, 0.f};
    }
    #pragma unroll
    for (int rf = 0; rf < 4; ++rf) {
        bf16x8 afrag[4];
        #pragma unroll
        for (int kc = 0; kc < 4; ++kc)
            afrag[kc] = *(const bf16x8*)&As[(rf * 16 + lrow) * ASTRIDE + kc * 32 + lk8];
        #pragma unroll
        for (int kc = 0; kc < 4; ++kc) {
            acc[rf][0] = __builtin_amdgcn_mfma_f32_16x16x32_bf16(afrag[kc], bfrag[0][kc], acc[rf][0], 0, 0, 0);
            acc[rf][1] = __builtin_amdgcn_mfma_f32_16x16x32_bf16(afrag[kc], bfrag[1][kc], acc[rf][1], 0, 0, 0);
        }
    }
    float alpha = 1.f / (1.f + __expf(-skip[0]));
    float om = 1.f - alpha;
    float bias0 = b[w * 32 + lrow];
    float bias1 = b[w * 32 + 16 + lrow];
    #pragma unroll
    for (int rf = 0; rf < 4; ++rf) {
        #pragma unroll
        for (int r = 0; r < 4; ++r) {
            int row = row0 + rf * 16 + (l >> 4) * 4 + r;
            if (row < N) {
                int c0 = w * 32 + lrow;
                float x0 = X[(size_t)row * D + c0];
                float x1 = X[(size_t)row * D + c0 + 16];
                O[(size_t)row * D + c0]      = (acc[rf][0][r] + bias0) * alpha + x0 * om;
                O[(size_t)row * D + c0 + 16] = (acc[rf][1][r] + bias1) * alpha + x1 * om;
            }
        }
    }
}

// ---------- combined CSR build over 3 etypes in slot space ----------
struct EdgeArgs {
    const int* src[3]; const int* dst[3]; int base[3]; int E;
};

__global__ __launch_bounds__(256) void hist_all_kernel(EdgeArgs a, int* __restrict__ cnt) {
    int gid = blockIdx.x * 256 + threadIdx.x;
    int E = a.E;
    if (gid >= 3 * E) return;
    int t = (gid < E) ? 0 : ((gid < 2 * E) ? 1 : 2);
    int e = gid - t * E;
    atomicAdd(&cnt[a.base[t] + a.dst[t][e]], 1);
}

__global__ __launch_bounds__(SCAN_BLK) void scan1_kernel(const int* __restrict__ cnt, int* __restrict__ bsum, int n) {
    __shared__ int sh[SCAN_BLK];
    int base = blockIdx.x * SCAN_TILE + threadIdx.x * SCAN_ITEMS;
    int s = 0;
    #pragma unroll
    for (int i = 0; i < SCAN_ITEMS; ++i) {
        int idx = base + i;
        if (idx < n) s += cnt[idx];
    }
    sh[threadIdx.x] = s; __syncthreads();
    for (int o = SCAN_BLK / 2; o > 0; o >>= 1) {
        if (threadIdx.x < o) sh[threadIdx.x] += sh[threadIdx.x + o];
        __syncthreads();
    }
    if (threadIdx.x == 0) bsum[blockIdx.x] = sh[0];
}

// scan3 with integrated block-prefix over bsum (no serial scan2 kernel)
__global__ __launch_bounds__(SCAN_BLK) void scan3_kernel(
    const int* __restrict__ cnt, const int* __restrict__ bsum,
    int* __restrict__ offs, int* __restrict__ cursor, int n)
{
    __shared__ int red[SCAN_BLK];
    __shared__ int sh[SCAN_BLK];
    const int tid = threadIdx.x;
    int pre = 0;
    for (int i = tid; i < blockIdx.x; i += SCAN_BLK) pre += bsum[i];
    red[tid] = pre; __syncthreads();
    for (int o = SCAN_BLK / 2; o > 0; o >>= 1) {
        if (tid < o) red[tid] += red[tid + o];
        __syncthreads();
    }
    int base0 = red[0];

    int base = blockIdx.x * SCAN_TILE + tid * SCAN_ITEMS;
    int v[SCAN_ITEMS];
    int s = 0;
    #pragma unroll
    for (int i = 0; i < SCAN_ITEMS; ++i) {
        int idx = base + i;
        v[i] = (idx < n) ? cnt[idx] : 0;
        s += v[i];
    }
    sh[tid] = s; __syncthreads();
    for (int o = 1; o < SCAN_BLK; o <<= 1) {
        int t = (tid >= o) ? sh[tid - o] : 0;
        __syncthreads();
        sh[tid] += t;
        __syncthreads();
    }
    int off = base0 + sh[tid] - s;
    #pragma unroll
    for (int i = 0; i < SCAN_ITEMS; ++i) {
        int idx = base + i;
        if (idx < n) {
            offs[idx] = off;
            cursor[idx] = off;
            off += v[i];
            if (idx == n - 1) offs[n] = off;
        }
    }
}

__global__ __launch_bounds__(256) void scatter_all_kernel(
    EdgeArgs a, int* __restrict__ cursor, int* __restrict__ csr_src)
{
    int gid = blockIdx.x * 256 + threadIdx.x;
    int E = a.E;
    if (gid >= 3 * E) return;
    int t = (gid < E) ? 0 : ((gid < 2 * E) ? 1 : 2);
    int e = gid - t * E;
    int p = atomicAdd(&cursor[a.base[t] + a.dst[t][e]], 1);
    csr_src[p] = a.src[t][e];
}

// ---------- fused per-dst softmax + aggregate over CSR segments, all etypes ----------
// KV layout: [src][head][k16|v16] (512B rows); per edge a thread reads 64B contiguous.
struct AggArgs {
    const unsigned short* KV[3];
    const unsigned short* Q[3];
    const float* pri[3];
    unsigned short* T[3];
};

__global__ __launch_bounds__(256) void csr_agg_all_kernel(
    const int* __restrict__ offs, const int* __restrict__ csr_src,
    AggArgs a, int n_b, int n_a)
{
    int gid = blockIdx.x * 256 + threadIdx.x;
    int s = gid >> 3, h = gid & 7;
    int S = 2 * n_b + n_a;
    if (s >= S) return;
    int t = (s < n_b) ? 0 : ((s < 2 * n_b) ? 1 : 2);
    int n = s - ((t == 2) ? 2 * n_b : t * n_b);

    const unsigned short *KVp, *Qp; const float* prip; unsigned short* Tp;
    if (t == 0)      { KVp=a.KV[0]; Qp=a.Q[0]; prip=a.pri[0]; Tp=a.T[0]; }
    else if (t == 1) { KVp=a.KV[1]; Qp=a.Q[1]; prip=a.pri[1]; Tp=a.T[1]; }
    else             { KVp=a.KV[2]; Qp=a.Q[2]; prip=a.pri[2]; Tp=a.T[2]; }

    int e0 = offs[s], e1 = offs[s + 1];

    const uint4* qp = (const uint4*)(Qp + (size_t)n * D + h * DK);
    uint4 q0 = qp[0], q1 = qp[1];
    float qv[16];
    unpack8(q0, qv); unpack8(q1, qv + 8);
    float ps = prip[h] * 0.25f;

    const uint4* kvbase = (const uint4*)KVp + h * 4;   // row stride = 32 uint4

    float acc[16];
    #pragma unroll
    for (int i = 0; i < 16; ++i) acc[i] = 0.f;
    float den = 0.f;

    int e = e0;
    for (; e + 2 <= e1; e += 2) {
        int s0 = csr_src[e], s1 = csr_src[e + 1];
        const uint4* p0 = kvbase + (size_t)s0 * 32;
        const uint4* p1 = kvbase + (size_t)s1 * 32;
        uint4 ka0 = p0[0], ka1 = p0[1], va0 = p0[2], va1 = p0[3];
        uint4 kb0 = p1[0], kb1 = p1[1], vb0 = p1[2], vb1 = p1[3];
        float k0v[16], k1v[16];
        unpack8(ka0, k0v); unpack8(ka1, k0v + 8);
        unpack8(kb0, k1v); unpack8(kb1, k1v + 8);
        float a0 = 0.f, a1 = 0.f;
        #pragma unroll
        for (int i = 0; i < 16; ++i) {
            a0 = fmaf(k0v[i], qv[i], a0);
            a1 = fmaf(k1v[i], qv[i], a1);
        }
        float ea0 = __expf(a0 * ps);
        float ea1 = __expf(a1 * ps);
        den += ea0 + ea1;
        float v0v[16], v1v[16];
        unpack8(va0, v0v); unpack8(va1, v0v + 8);
        unpack8(vb0, v1v); unpack8(vb1, v1v + 8);
        #pragma unroll
        for (int i = 0; i < 16; ++i)
            acc[i] = fmaf(ea0, v0v[i], fmaf(ea1, v1v[i], acc[i]));
    }
    if (e < e1) {
        int s0 = csr_src[e];
        const uint4* p0 = kvbase + (size_t)s0 * 32;
        uint4 ka0 = p0[0], ka1 = p0[1], va0 = p0[2], va1 = p0[3];
        float k0v[16];
        unpack8(ka0, k0v); unpack8(ka1, k0v + 8);
        float a0 = 0.f;
        #pragma unroll
        for (int i = 0; i < 16; ++i) a0 = fmaf(k0v[i], qv[i], a0);
        float ea0 = __expf(a0 * ps);
        den += ea0;
        float v0v[16];
        unpack8(va0, v0v); unpack8(va1, v0v + 8);
        #pragma unroll
        for (int i = 0; i < 16; ++i) acc[i] = fmaf(ea0, v0v[i], acc[i]);
    }

    float inv = 1.f / fmaxf(den, 1e-9f);
    unsigned short ob[16];
    #pragma unroll
    for (int i = 0; i < 16; ++i) ob[i] = f2bf(acc[i] * inv);
    uint4 o0, o1;
    o0.x = pack2(ob[0], ob[1]);   o0.y = pack2(ob[2], ob[3]);
    o0.z = pack2(ob[4], ob[5]);   o0.w = pack2(ob[6], ob[7]);
    o1.x = pack2(ob[8], ob[9]);   o1.y = pack2(ob[10], ob[11]);
    o1.z = pack2(ob[12], ob[13]); o1.w = pack2(ob[14], ob[15]);
    unsigned short* tp = Tp + (size_t)n * D + h * DK;
    *(uint4*)tp = o0;
    *(uint4*)(tp + 8) = o1;
}

extern "C" void kernel_launch(void* const* d_in, const int* in_sizes, int n_in,
                              void* d_out, int out_size, void* d_ws, size_t ws_size,
                              hipStream_t stream) {
    const float* x_a = (const float*)d_in[0];
    const float* x_b = (const float*)d_in[1];
    const int* src_ab = (const int*)d_in[2];
    const int* dst_ab = (const int*)d_in[3];
    const int* src_ba = (const int*)d_in[4];
    const int* dst_ba = (const int*)d_in[5];
    const int* src_bb = (const int*)d_in[6];
    const int* dst_bb = (const int*)d_in[7];
    const float* Wk_a = (const float*)d_in[8];  const float* bk_a = (const float*)d_in[9];
    const float* Wq_a = (const float*)d_in[10]; const float* bq_a = (const float*)d_in[11];
    const float* Wv_a = (const float*)d_in[12]; const float* bv_a = (const float*)d_in[13];
    const float* Wa_a = (const float*)d_in[14]; const float* ba_a = (const float*)d_in[15];
    const float* skip_a = (const float*)d_in[16];
    const float* Wk_b = (const float*)d_in[17]; const float* bk_b = (const float*)d_in[18];
    const float* Wq_b = (const float*)d_in[19]; const float* bq_b = (const float*)d_in[20];
    const float* Wv_b = (const float*)d_in[21]; const float* bv_b = (const float*)d_in[22];
    const float* Wa_b = (const float*)d_in[23]; const float* ba_b = (const float*)d_in[24];
    const float* skip_b = (const float*)d_in[25];
    const float* pri_ab = (const float*)d_in[26];
    const float* att_ab = (const float*)d_in[27];
    const float* msg_ab = (const float*)d_in[28];
    const float* pri_ba = (const float*)d_in[29];
    const float* att_ba = (const float*)d_in[30];
    const float* msg_ba = (const float*)d_in[31];
    const float* pri_bb = (const float*)d_in[32];
    const float* att_bb = (const float*)d_in[33];
    const float* msg_bb = (const float*)d_in[34];

    const int n_a = in_sizes[0] / D;
    const int n_b = in_sizes[1] / D;
    const int E = in_sizes[2];
    const int S = 2 * n_b + n_a;

    size_t off = 0;
    char* base = (char*)d_ws;
    auto alloc = [&](size_t bytes) -> void* {
        void* r = base + off;
        off += (bytes + 255) & ~(size_t)255;
        return r;
    };
    unsigned short* kv_ab = (unsigned short*)alloc((size_t)n_a * 256 * 2);  // k_a | vab
    unsigned short* kv_bb = (unsigned short*)alloc((size_t)n_b * 256 * 2);  // k_b | vbb
    unsigned short* kv_ba = (unsigned short*)alloc((size_t)n_b * 256 * 2);  // k_b | vba
    unsigned short* qab = (unsigned short*)alloc((size_t)n_b * D * 2);
    unsigned short* qbb = (unsigned short*)alloc((size_t)n_b * D * 2);
    unsigned short* qba = (unsigned short*)alloc((size_t)n_a * D * 2);
    unsigned short* t_a  = (unsigned short*)alloc((size_t)n_a * D * 2);
    unsigned short* t_b1 = (unsigned short*)alloc((size_t)n_b * D * 2);
    unsigned short* t_b2 = (unsigned short*)alloc((size_t)n_b * D * 2);
    int* cnt    = (int*)alloc((size_t)S * 4);
    int* offs   = (int*)alloc(((size_t)S + 1) * 4);
    int* cursor = (int*)alloc((size_t)S * 4);
    int* csr_src= (int*)alloc((size_t)3 * E * 4);
    int* bsum   = (int*)alloc(256 * 4);
    unsigned short* wt_plain[4];
    for (int i = 0; i < 4; ++i) wt_plain[i] = (unsigned short*)alloc((size_t)D * D * 2);
    unsigned short* wt_fold[6];
    float* bf_fold[6];
    for (int i = 0; i < 6; ++i) {
        wt_fold[i] = (unsigned short*)alloc((size_t)D * D * 2);
        bf_fold[i] = (float*)alloc((size_t)D * 4);
    }

    // prep: transposes (Wk_a, Wk_b, Wa_a, Wa_b), folds, zero cnt
    WTIn win; WTOut wout;
    const float* worig[4] = {Wk_a, Wk_b, Wa_a, Wa_b};
    for (int i = 0; i < 4; ++i) { win.w[i] = worig[i]; wout.wt[i] = wt_plain[i]; }
    FoldArgs fa;
    const float* fW[6] = {Wq_b, Wq_b, Wq_a, Wv_a, Wv_b, Wv_b};
    const float* fR[6] = {att_ab, att_bb, att_ba, msg_ab, msg_bb, msg_ba};
    const float* fb[6] = {bq_b, bq_b, bq_a, bv_a, bv_b, bv_b};
    int fm[6] = {0, 0, 0, 1, 1, 1};
    for (int i = 0; i < 6; ++i) {
        fa.W[i] = fW[i]; fa.R[i] = fR[i]; fa.b[i] = fb[i];
        fa.WT[i] = wt_fold[i]; fa.bf[i] = bf_fold[i]; fa.mode[i] = fm[i];
    }
    int nz = (S + 1023) / 1024;
    prep_kernel<<<112 + nz, 256, 0, stream>>>(win, wout, fa, cnt, S);

    // combined CSR build
    EdgeArgs ea;
    ea.src[0] = src_ab; ea.dst[0] = dst_ab;
    ea.src[1] = src_bb; ea.dst[1] = dst_bb;
    ea.src[2] = src_ba; ea.dst[2] = dst_ba;
    ea.base[0] = 0; ea.base[1] = n_b; ea.base[2] = 2 * n_b;
    ea.E = E;
    int ge3 = (3 * E + 255) / 256;
    hist_all_kernel<<<ge3, 256, 0, stream>>>(ea, cnt);
    int nb = (S + SCAN_TILE - 1) / SCAN_TILE;
    scan1_kernel<<<nb, SCAN_BLK, 0, stream>>>(cnt, bsum, S);
    scan3_kernel<<<nb, SCAN_BLK, 0, stream>>>(cnt, bsum, offs, cursor, S);
    scatter_all_kernel<<<ge3, 256, 0, stream>>>(ea, cursor, csr_src);

    // projections with folded weights, KV-interleaved outputs
    const int gb_a = (n_a + 63) / 64;
    const int gb_b = (n_b + 63) / 64;
    {
        ProjArgs<3> pa;
        pa.wt[0] = wt_plain[0]; pa.bias[0] = bk_a;       pa.out[0] = kv_ab; pa.mode[0] = 1; pa.out2[0] = nullptr; pa.mode2[0] = 0;
        pa.wt[1] = wt_fold[2];  pa.bias[1] = bf_fold[2]; pa.out[1] = qba;   pa.mode[1] = 0; pa.out2[1] = nullptr; pa.mode2[1] = 0;
        pa.wt[2] = wt_fold[3];  pa.bias[2] = bf_fold[3]; pa.out[2] = kv_ab; pa.mode[2] = 2; pa.out2[2] = nullptr; pa.mode2[2] = 0;
        proj_all_kernel<3><<<gb_a, 256, 0, stream>>>(x_a, pa, n_a);
    }
    {
        ProjArgs<5> pb;
        pb.wt[0] = wt_plain[1]; pb.bias[0] = bk_b;       pb.out[0] = kv_bb; pb.mode[0] = 1; pb.out2[0] = kv_ba;  pb.mode2[0] = 1;
        pb.wt[1] = wt_fold[0];  pb.bias[1] = bf_fold[0]; pb.out[1] = qab;   pb.mode[1] = 0; pb.out2[1] = nullptr; pb.mode2[1] = 0;
        pb.wt[2] = wt_fold[1];  pb.bias[2] = bf_fold[1]; pb.out[2] = qbb;   pb.mode[2] = 0; pb.out2[2] = nullptr; pb.mode2[2] = 0;
        pb.wt[3] = wt_fold[4];  pb.bias[3] = bf_fold[4]; pb.out[3] = kv_bb; pb.mode[3] = 2; pb.out2[3] = nullptr; pb.mode2[3] = 0;
        pb.wt[4] = wt_fold[5];  pb.bias[4] = bf_fold[5]; pb.out[4] = kv_ba; pb.mode[4] = 2; pb.out2[4] = nullptr; pb.mode2[4] = 0;
        proj_all_kernel<5><<<gb_b, 256, 0, stream>>>(x_b, pb, n_b);
    }

    // fused aggregate (all etypes)
    AggArgs aa;
    aa.KV[0] = kv_ab; aa.Q[0] = qab; aa.pri[0] = pri_ab; aa.T[0] = t_b1;
    aa.KV[1] = kv_bb; aa.Q[1] = qbb; aa.pri[1] = pri_bb; aa.T[1] = t_b2;
    aa.KV[2] = kv_ba; aa.Q[2] = qba; aa.pri[2] = pri_ba; aa.T[2] = t_a;
    int gs = (S * H + 255) / 256;
    csr_agg_all_kernel<<<gs, 256, 0, stream>>>(offs, csr_src, aa, n_b, n_a);

    // final skip-connection GEMMs (MFMA)
    float* out_a = (float*)d_out;
    float* out_b = (float*)d_out + (size_t)n_a * D;
    out_gemm_mfma_kernel<1><<<gb_a, 256, 0, stream>>>(t_a, nullptr, wt_plain[2], ba_a, skip_a, x_a, out_a, n_a);
    out_gemm_mfma_kernel<2><<<gb_b, 256, 0, stream>>>(t_b1, t_b2, wt_plain[3], ba_b, skip_b, x_b, out_b, n_b);
}